// Round 7
// baseline (858.500 us; speedup 1.0000x reference)
//
#include <hip/hip_runtime.h>

#define Bn 256
#define Tn 512
#define Vn 64
#define Hn 256
#define INn 129
#define Cc 8                 // timesteps per chunk (fallback path)
#define NCH (Tn / Cc)
#define WU 68                // packed uints per W_ih row (136 f16 cols)
#define WSZ (768 * WU)       // uints for packed W_ih
#define GX_OFF (262144)      // byte offset of gx in ws
#define GX_BYTES ((size_t)Bn * Tn * 768 * 2)
#define AST 168              // A-tile LDS stride in halves (staging)
#define CST 264              // C-tile LDS stride in halves (epilogue transpose)

typedef __fp16 half2_t __attribute__((ext_vector_type(2)));
typedef __fp16 half8_t __attribute__((ext_vector_type(8)));
typedef float f32x4 __attribute__((ext_vector_type(4)));

static __device__ __forceinline__ unsigned int cvt2(float a, float b) {
  return __builtin_bit_cast(unsigned int, __builtin_amdgcn_cvt_pkrtz(a, b));
}

static __device__ __forceinline__ float dot2(unsigned int w, unsigned int x, float acc) {
#if __has_builtin(__builtin_amdgcn_fdot2)
  return __builtin_amdgcn_fdot2(__builtin_bit_cast(half2_t, w),
                                __builtin_bit_cast(half2_t, x), acc, false);
#else
  half2_t a = __builtin_bit_cast(half2_t, w);
  half2_t b = __builtin_bit_cast(half2_t, x);
  return acc + (float)a.x * (float)b.x + (float)a.y * (float)b.y;
#endif
}

// pair-sum across lanes 2i<->2i+1 (DPP quad_perm [1,0,3,2])
static __device__ __forceinline__ float pair_sum(float v) {
#if __has_builtin(__builtin_amdgcn_update_dpp)
  int x = __builtin_amdgcn_update_dpp(0, __builtin_bit_cast(int, v), 0xB1, 0xF, 0xF, true);
  return v + __builtin_bit_cast(float, x);
#else
  int j = __builtin_amdgcn_ds_swizzle(__builtin_bit_cast(int, v), 0x041F);
  return v + __builtin_bit_cast(float, j);
#endif
}

// full sum across each aligned group of 4 lanes (xor1 then xor2, both quad_perm DPP)
static __device__ __forceinline__ float quad_sum(float v) {
#if __has_builtin(__builtin_amdgcn_update_dpp)
  int x = __builtin_amdgcn_update_dpp(0, __builtin_bit_cast(int, v), 0xB1, 0xF, 0xF, true);
  v += __builtin_bit_cast(float, x);
  int y = __builtin_amdgcn_update_dpp(0, __builtin_bit_cast(int, v), 0x4E, 0xF, 0xF, true);
  v += __builtin_bit_cast(float, y);
  return v;
#else
  int j = __builtin_amdgcn_ds_swizzle(__builtin_bit_cast(int, v), 0x041F);
  v += __builtin_bit_cast(float, j);
  j = __builtin_amdgcn_ds_swizzle(__builtin_bit_cast(int, v), 0x081F);
  v += __builtin_bit_cast(float, j);
  return v;
#endif
}

static __device__ __forceinline__ float fast_exp2(float x) {
#if __has_builtin(__builtin_amdgcn_exp2f)
  return __builtin_amdgcn_exp2f(x);
#else
  return exp2f(x);
#endif
}
static __device__ __forceinline__ float fast_rcp(float x) {
#if __has_builtin(__builtin_amdgcn_rcpf)
  return __builtin_amdgcn_rcpf(x);
#else
  return 1.f / x;
#endif
}
static __device__ __forceinline__ float sigmoid_f(float x) {
  return fast_rcp(1.f + fast_exp2(-1.44269504f * x));
}
static __device__ __forceinline__ float tanh_f(float x) {
  return 1.f - 2.f * fast_rcp(1.f + fast_exp2(2.88539008f * x));
}

// Pack W_ih (768x129 f32) into [768][68] f16-pair uints in workspace (cols >=129 zero).
__global__ void convert_wih(const float* __restrict__ W_ih, unsigned int* __restrict__ w16) {
  int idx = blockIdx.x * 256 + threadIdx.x;
  if (idx >= WSZ) return;
  int j = idx / WU, c = idx - j * WU;
  int col = 2 * c;
  float f0 = (col < INn) ? W_ih[(size_t)j * INn + col] : 0.f;
  float f1 = (col + 1 < INn) ? W_ih[(size_t)j * INn + col + 1] : 0.f;
  w16[idx] = cvt2(f0, f1);
}

// ---------------- GEMM: gx[b][t][n] = x[b][t] . W_ih[n] + b_ih[n]  (f16 out) -------------
__global__ __launch_bounds__(256, 4)
void gx_gemm(const float* __restrict__ times_in, const float* __restrict__ data_in,
             const float* __restrict__ mask_in, const unsigned int* __restrict__ w16,
             const float* __restrict__ b_ih, __fp16* __restrict__ gx) {
  __shared__ __align__(16) char raw[64 * CST * 2];  // staging (stride AST) then C-tile (stride CST)
  __fp16* xa = (__fp16*)raw;
  __fp16* ct = (__fp16*)raw;

  const int tid = threadIdx.x;
  const int bt = blockIdx.x;
  const int b = bt >> 3, tc = bt & 7;
  const int t0 = tc * 64;
  const int n0 = blockIdx.y * 256;

  // ---- stage A: 64 rows x {data(64)|mask(64)|delta|pad} halves, f32->f16 ----
  {
    int r = tid >> 2, s = tid & 3;
    const float* src = (s < 2)
        ? data_in + ((size_t)b * Tn + t0 + r) * Vn + s * 32
        : mask_in + ((size_t)b * Tn + t0 + r) * Vn + (s - 2) * 32;
    unsigned int* dst = (unsigned int*)(xa + r * AST) + s * 16;
#pragma unroll
    for (int i = 0; i < 8; ++i) {
      float4 v = ((const float4*)src)[i];
      dst[2 * i] = cvt2(v.x, v.y);
      dst[2 * i + 1] = cvt2(v.z, v.w);
    }
  }
  if (tid < 64) {
    int g = t0 + tid;
    float tcur = times_in[(size_t)b * Tn + g];
    float d = (g < Tn - 1) ? times_in[(size_t)b * Tn + g + 1] - tcur : 0.f;
    unsigned int* p = (unsigned int*)(xa + tid * AST + 128);
    p[0] = cvt2(d, 0.f);
#pragma unroll
    for (int i = 1; i < 20; ++i) p[i] = 0u;
  }
  __syncthreads();

  const int w = tid >> 6, lane = tid & 63;
  const int m = lane & 15, q = lane >> 4;
  const int nw = n0 + w * 64;

  f32x4 acc[4][4];
#pragma unroll
  for (int i = 0; i < 4; ++i)
#pragma unroll
    for (int j = 0; j < 4; ++j) acc[i][j] = f32x4{0.f, 0.f, 0.f, 0.f};

#pragma unroll
  for (int kt = 0; kt < 5; ++kt) {
    const int k0 = kt * 32 + q * 8;
    half8_t bf[4], af[4];
#pragma unroll
    for (int nt = 0; nt < 4; ++nt) {
      int n = nw + nt * 16 + m;
      uint4 bv = *(const uint4*)(w16 + (size_t)n * WU + (k0 >> 1));
      bf[nt] = __builtin_bit_cast(half8_t, bv);
    }
#pragma unroll
    for (int mt = 0; mt < 4; ++mt) {
      uint4 av = *(const uint4*)(xa + (mt * 16 + m) * AST + k0);
      af[mt] = __builtin_bit_cast(half8_t, av);
    }
#pragma unroll
    for (int mt = 0; mt < 4; ++mt)
#pragma unroll
      for (int nt = 0; nt < 4; ++nt)
        acc[mt][nt] = __builtin_amdgcn_mfma_f32_16x16x32_f16(af[mt], bf[nt], acc[mt][nt], 0, 0, 0);
  }

  float bias[4];
#pragma unroll
  for (int nt = 0; nt < 4; ++nt) bias[nt] = b_ih[nw + nt * 16 + m];

  __syncthreads();  // staging reads done; reuse LDS as C-tile
#pragma unroll
  for (int mt = 0; mt < 4; ++mt)
#pragma unroll
    for (int nt = 0; nt < 4; ++nt)
#pragma unroll
      for (int r = 0; r < 4; ++r)
        ct[(mt * 16 + q * 4 + r) * CST + w * 64 + nt * 16 + m] =
            (__fp16)(acc[mt][nt][r] + bias[nt]);
  __syncthreads();

  {
    const int tt = tid >> 2, qq = tid & 3;
    const uint4* src = (const uint4*)(ct + tt * CST) + qq * 8;
    uint4* dst = (uint4*)(gx + ((size_t)b * Tn + t0 + tt) * 768 + n0) + qq * 8;
#pragma unroll
    for (int i = 0; i < 8; ++i) dst[i] = src[i];
  }
}

// ---------------- Scan v4: 1024 threads, 4-way k-split, 96 weight uints/thread ------------
// R4-R6 evidence: with 192 weight uints/thread the allocator pins arch VGPRs at 128 and
// AGPR-allocates the weights -> per-use copy tax (~190 VALU/step/wave). Here the k-quarter
// split drops demand to ~150 so nearly everything fits the 128-reg budget that 16 waves get.
#define DOT4(hv, base)                                                                     \
  sr = dot2(whr[(base) + 0], hv.x, sr); sz = dot2(whz[(base) + 0], hv.x, sz);              \
  shn = dot2(whn[(base) + 0], hv.x, shn);                                                  \
  sr = dot2(whr[(base) + 1], hv.y, sr); sz = dot2(whz[(base) + 1], hv.y, sz);              \
  shn = dot2(whn[(base) + 1], hv.y, shn);                                                  \
  sr = dot2(whr[(base) + 2], hv.z, sr); sz = dot2(whz[(base) + 2], hv.z, sz);              \
  shn = dot2(whn[(base) + 2], hv.z, shn);                                                  \
  sr = dot2(whr[(base) + 3], hv.w, sr); sz = dot2(whz[(base) + 3], hv.w, sz);              \
  shn = dot2(whn[(base) + 3], hv.w, shn);

__global__ __launch_bounds__(1024, 1)
void gru_scan4(const float* __restrict__ times_in, const float* __restrict__ W_hh,
               const float* __restrict__ b_hh, const __fp16* __restrict__ gx,
               float* __restrict__ out) {
  __shared__ __align__(16) __fp16 h_buf[2 * Hn];
  __shared__ __align__(16) float t_lds[Tn];

  const int tid = threadIdx.x;
  const int b = blockIdx.x;
  const int jg = tid >> 2;  // hidden index 0..255
  const int ks = tid & 3;   // k-quarter 0..3

  if (tid < Tn) t_lds[tid] = times_in[(size_t)b * Tn + tid];

  // Register-resident W_hh k-quarter (f16 pairs; 96 uints/thread)
  unsigned int whr[32], whz[32], whn[32];
  {
    const float* w0 = W_hh + (size_t)jg * Hn + ks * 64;
    const float* w1 = W_hh + (size_t)(jg + 256) * Hn + ks * 64;
    const float* w2 = W_hh + (size_t)(jg + 512) * Hn + ks * 64;
#pragma unroll
    for (int c = 0; c < 32; ++c) {
      whr[c] = cvt2(w0[2 * c], w0[2 * c + 1]);
      whz[c] = cvt2(w1[2 * c], w1[2 * c + 1]);
      whn[c] = cvt2(w2[2 * c], w2[2 * c + 1]);
    }
  }
  const float brh = b_hh[jg];
  const float bzh = b_hh[jg + 256];
  const float bhn = b_hh[jg + 512];

  if (tid < 2 * Hn) h_buf[tid] = (__fp16)0.f;
  __syncthreads();

  const __fp16* gxb = gx + (size_t)b * Tn * 768;
  float hcur = 0.f;

  float gr = (float)gxb[jg], gz = (float)gxb[256 + jg], gn = (float)gxb[512 + jg];
  float mt = t_lds[0];

#pragma unroll 1
  for (int t = 0; t < Tn; ++t) {
    // branchless prefetch of step t+1 (clamped; last-iter values unused)
    const int tn = (t + 1 < Tn) ? (t + 1) : (Tn - 1);
    const __fp16* p = gxb + (size_t)tn * 768;
    __fp16 pr = p[jg], pz = p[256 + jg], pn = p[512 + jg];
    float mtn = t_lds[tn];

    const int cur = t & 1;
    const uint4* hb = (const uint4*)(h_buf + cur * Hn) + ks * 8;  // 128 B = this thread's k-quarter

    float sr = 0.f, sz = 0.f, shn = 0.f;
    {
      uint4 h0 = hb[0], h1 = hb[1], h2 = hb[2], h3 = hb[3];
      DOT4(h0, 0) DOT4(h1, 4) DOT4(h2, 8) DOT4(h3, 12)
    }
    {
      uint4 h4 = hb[4], h5 = hb[5], h6 = hb[6], h7 = hb[7];
      DOT4(h4, 16) DOT4(h5, 20) DOT4(h6, 24) DOT4(h7, 28)
    }

    // reduce the four k-quarters on the VALU pipe (2-hop DPP)
    sr = quad_sum(sr);
    sz = quad_sum(sz);
    shn = quad_sum(shn);

    float r = sigmoid_f(gr + sr + brh);
    float z = sigmoid_f(gz + sz + bzh);
    float n = tanh_f(gn + r * (shn + bhn));
    float hN = (1.f - z) * n + z * hcur;
    hcur = (mt > 0.f) ? hN : hcur;

    if (ks == 0) h_buf[(cur ^ 1) * Hn + jg] = (__fp16)hcur;
    __syncthreads();

    gr = (float)pr; gz = (float)pz; gn = (float)pn; mt = mtn;
  }

  if (ks == 0) out[(size_t)b * Hn + jg] = hcur;
}

// ---------------- Fallback (R3): in-kernel phase A, used only if ws too small -------------
template <bool USE_WS>
static __device__ __forceinline__ void phaseA_pass(int col, const unsigned int* __restrict__ w16,
                                                   const float* __restrict__ W_ih,
                                                   const unsigned int* x_lds, float* a) {
  const uint4* wp = (const uint4*)(w16) + (size_t)col * (WU / 4);
  const float* wf = W_ih + (size_t)col * INn;
#pragma unroll 2
  for (int kp = 0; kp < 8; ++kp) {
    uint4 wa, wb;
    if constexpr (USE_WS) {
      wa = wp[2 * kp];
      wb = wp[2 * kp + 1];
    } else {
      const float* f = wf + 16 * kp;
      wa.x = cvt2(f[0], f[1]);   wa.y = cvt2(f[2], f[3]);
      wa.z = cvt2(f[4], f[5]);   wa.w = cvt2(f[6], f[7]);
      wb.x = cvt2(f[8], f[9]);   wb.y = cvt2(f[10], f[11]);
      wb.z = cvt2(f[12], f[13]); wb.w = cvt2(f[14], f[15]);
    }
#pragma unroll
    for (int t = 0; t < Cc; ++t) {
      const uint4* xp = (const uint4*)&x_lds[t * WU + kp * 8];
      uint4 xa = xp[0], xb = xp[1];
      a[t] = dot2(wa.x, xa.x, a[t]);
      a[t] = dot2(wa.y, xa.y, a[t]);
      a[t] = dot2(wa.z, xa.z, a[t]);
      a[t] = dot2(wa.w, xa.w, a[t]);
      a[t] = dot2(wb.x, xb.x, a[t]);
      a[t] = dot2(wb.y, xb.y, a[t]);
      a[t] = dot2(wb.z, xb.z, a[t]);
      a[t] = dot2(wb.w, xb.w, a[t]);
    }
  }
  uint4 wt;
  if constexpr (USE_WS) {
    wt = wp[16];
  } else {
    wt.x = cvt2(wf[128], 0.f); wt.y = 0u; wt.z = 0u; wt.w = 0u;
  }
#pragma unroll
  for (int t = 0; t < Cc; ++t) {
    uint4 xt = *(const uint4*)&x_lds[t * WU + 64];
    a[t] = dot2(wt.x, xt.x, a[t]);
    a[t] = dot2(wt.y, xt.y, a[t]);
  }
}

template <bool USE_WS>
__global__ __launch_bounds__(512, 2)
void gru_scan_fb(const float* __restrict__ times_in, const float* __restrict__ data_in,
                 const float* __restrict__ mask_in, const unsigned int* __restrict__ w16,
                 const float* __restrict__ W_ih, const float* __restrict__ W_hh,
                 const float* __restrict__ b_ih, const float* __restrict__ b_hh,
                 float* __restrict__ out) {
  __shared__ __align__(16) float gx_lds[Cc * 768];
  __shared__ __align__(16) unsigned int x_lds[Cc * WU];
  __shared__ __align__(16) __fp16 h_buf[2 * Hn];
  __shared__ __align__(16) float t_lds[Tn];

  const int tid = threadIdx.x;
  const int b = blockIdx.x;
  const int jg = tid >> 1;
  const int ks = tid & 1;

  t_lds[tid] = times_in[(size_t)b * Tn + tid];

  unsigned int whr[64], whz[64], whn[64];
  {
    const float* w0 = W_hh + (size_t)jg * Hn + ks * 128;
    const float* w1 = W_hh + (size_t)(jg + 256) * Hn + ks * 128;
    const float* w2 = W_hh + (size_t)(jg + 512) * Hn + ks * 128;
#pragma unroll
    for (int c = 0; c < 64; ++c) {
      whr[c] = cvt2(w0[2 * c], w0[2 * c + 1]);
      whz[c] = cvt2(w1[2 * c], w1[2 * c + 1]);
      whn[c] = cvt2(w2[2 * c], w2[2 * c + 1]);
    }
  }
  const float brh = b_hh[jg];
  const float bzh = b_hh[jg + 256];
  const float bhn = b_hh[jg + 512];
  const float bi1 = b_ih[tid];
  const float bi2 = (tid < 256) ? b_ih[512 + tid] : 0.f;

  h_buf[tid] = (__fp16)0.f;
  __syncthreads();

  float hcur = 0.f;
  int cur = 0;
#pragma unroll 1
  for (int ch = 0; ch < NCH; ++ch) {
    const int t0 = ch * Cc;
    {
      int t = tid >> 6;
      int c = tid & 63;
      const float* src = (c < 32)
          ? data_in + ((size_t)b * Tn + t0 + t) * Vn + 2 * c
          : mask_in + ((size_t)b * Tn + t0 + t) * Vn + 2 * (c - 32);
      float2 v = *(const float2*)src;
      x_lds[t * WU + c] = cvt2(v.x, v.y);
      if (tid < Cc) {
        int g = t0 + tid;
        float d = (g < Tn - 1) ? (t_lds[g + 1] - t_lds[g]) : 0.f;
        uint4 tl;
        tl.x = cvt2(d, 0.f); tl.y = 0u; tl.z = 0u; tl.w = 0u;
        *(uint4*)&x_lds[tid * WU + 64] = tl;
      }
    }
    __syncthreads();
    {
      float a[Cc];
#pragma unroll
      for (int t = 0; t < Cc; ++t) a[t] = bi1;
      phaseA_pass<USE_WS>(tid, w16, W_ih, x_lds, a);
#pragma unroll
      for (int t = 0; t < Cc; ++t) gx_lds[t * 768 + tid] = a[t];
      if (tid < 256) {
#pragma unroll
        for (int t = 0; t < Cc; ++t) a[t] = bi2;
        phaseA_pass<USE_WS>(512 + tid, w16, W_ih, x_lds, a);
#pragma unroll
        for (int t = 0; t < Cc; ++t) gx_lds[t * 768 + 512 + tid] = a[t];
      }
    }
    __syncthreads();
    for (int tt = 0; tt < Cc; ++tt) {
      float sr = 0.f, sz = 0.f, shn = 0.f;
      const uint4* hb = (const uint4*)(h_buf + cur * Hn + ks * 128);
#pragma unroll
      for (int c = 0; c < 16; ++c) {
        uint4 hv = hb[c];
        sr = dot2(whr[4 * c + 0], hv.x, sr);
        sz = dot2(whz[4 * c + 0], hv.x, sz);
        shn = dot2(whn[4 * c + 0], hv.x, shn);
        sr = dot2(whr[4 * c + 1], hv.y, sr);
        sz = dot2(whz[4 * c + 1], hv.y, sz);
        shn = dot2(whn[4 * c + 1], hv.y, shn);
        sr = dot2(whr[4 * c + 2], hv.z, sr);
        sz = dot2(whz[4 * c + 2], hv.z, sz);
        shn = dot2(whn[4 * c + 2], hv.z, shn);
        sr = dot2(whr[4 * c + 3], hv.w, sr);
        sz = dot2(whz[4 * c + 3], hv.w, sz);
        shn = dot2(whn[4 * c + 3], hv.w, shn);
      }
      float gxr = gx_lds[tt * 768 + jg];
      float gxz = gx_lds[tt * 768 + 256 + jg];
      float gxn = gx_lds[tt * 768 + 512 + jg];
      sr = pair_sum(sr);
      sz = pair_sum(sz);
      shn = pair_sum(shn);
      float r = sigmoid_f(gxr + sr + brh);
      float z = sigmoid_f(gxz + sz + bzh);
      float n = tanh_f(gxn + r * (shn + bhn));
      float hN = (1.f - z) * n + z * hcur;
      hcur = (t_lds[t0 + tt] > 0.f) ? hN : hcur;
      if (ks == 0) h_buf[(cur ^ 1) * Hn + jg] = (__fp16)hcur;
      __syncthreads();
      cur ^= 1;
    }
  }
  if (ks == 0) out[(size_t)b * Hn + jg] = hcur;
}

extern "C" void kernel_launch(void* const* d_in, const int* in_sizes, int n_in,
                              void* d_out, int out_size, void* d_ws, size_t ws_size,
                              hipStream_t stream) {
  const float* times_in = (const float*)d_in[0];
  const float* data_in = (const float*)d_in[1];
  const float* mask_in = (const float*)d_in[2];
  const float* W_ih = (const float*)d_in[3];
  const float* W_hh = (const float*)d_in[4];
  const float* b_ih = (const float*)d_in[5];
  const float* b_hh = (const float*)d_in[6];
  float* out = (float*)d_out;

  unsigned int* w16 = (unsigned int*)d_ws;
  __fp16* gx = (__fp16*)((char*)d_ws + GX_OFF);

  if (ws_size >= GX_OFF + GX_BYTES) {
    hipLaunchKernelGGL(convert_wih, dim3((WSZ + 255) / 256), dim3(256), 0, stream, W_ih, w16);
    hipLaunchKernelGGL(gx_gemm, dim3(2048, 3), dim3(256), 0, stream,
                       times_in, data_in, mask_in, w16, b_ih, gx);
    hipLaunchKernelGGL(gru_scan4, dim3(Bn), dim3(1024), 0, stream,
                       times_in, W_hh, b_hh, gx, out);
  } else if (ws_size >= (size_t)WSZ * 4) {
    hipLaunchKernelGGL(convert_wih, dim3((WSZ + 255) / 256), dim3(256), 0, stream, W_ih, w16);
    hipLaunchKernelGGL((gru_scan_fb<true>), dim3(Bn), dim3(512), 0, stream,
                       times_in, data_in, mask_in, w16, W_ih, W_hh, b_ih, b_hh, out);
  } else {
    hipLaunchKernelGGL((gru_scan_fb<false>), dim3(Bn), dim3(512), 0, stream,
                       times_in, data_in, mask_in, (const unsigned int*)nullptr, W_ih, W_hh,
                       b_ih, b_hh, out);
  }
}